// Round 1
// baseline (1703.766 us; speedup 1.0000x reference)
//
#include <hip/hip_runtime.h>
#include <math.h>

// TfLSTM: x[512,256,128] -> LSTM(100, relu) -> LSTM(128, relu, last) -> Dense(19) -> softmax
// Strategy (round 0, fp32 baseline):
//   One block per batch row, persistent over all 256 timesteps. Thread k owns
//   gate column k; its W and U weight columns live in VGPRs (loaded once).
//   Per step: z[k] = b[k] + x_t . Wcol[k] + h . Ucol[k]  (LDS broadcast reads of
//   x_t / h, register-resident weights), activation, funnel gates through LDS,
//   c/h update by the first H threads. 2 barriers per step.
//   Workspace: h1_seq [T][B][100] f32 (52.4 MB) + h2 [B][128] (0.26 MB).

#define T_SEQ 256
#define BATCH 512
#define IN_DIM 128
#define H1 100
#define H2 128
#define NCLS 19

__device__ __forceinline__ float sigmoidf_(float x) {
    return 1.0f / (1.0f + __expf(-x));
}

// ---------------- LSTM layer 1 ----------------
// grid: 512 blocks (one batch row each), block: 448 threads (7 waves),
// threads k<400 active as gate-column owners.
__global__ __launch_bounds__(448, 1)
void lstm1_kernel(const float* __restrict__ x,   // [B][T][128]
                  const float* __restrict__ W1,  // [128][400] row-major
                  const float* __restrict__ U1,  // [100][400]
                  const float* __restrict__ b1,  // [400]
                  float* __restrict__ h1out)     // [T][B][100]
{
    const int b = blockIdx.x;
    const int k = threadIdx.x;

    __shared__ __align__(16) float xs[IN_DIM];  // staged x row
    __shared__ __align__(16) float hs[H1];      // hidden state
    __shared__ __align__(16) float zs[4 * H1];  // gate funnel

    // ---- load weight columns into registers (one-time) ----
    float w1r[IN_DIM];
    float u1r[H1];
    float bias = 0.0f;
    if (k < 4 * H1) {
        bias = b1[k];
#pragma unroll
        for (int d = 0; d < IN_DIM; ++d) w1r[d] = W1[d * (4 * H1) + k];
#pragma unroll
        for (int j = 0; j < H1; ++j) u1r[j] = U1[j * (4 * H1) + k];
    }

    // ---- init state + stage x(t=0) ----
    if (k < H1) hs[k] = 0.0f;
    if (k < IN_DIM / 4) {
        const float4* xrow = (const float4*)(x + ((size_t)b * T_SEQ + 0) * IN_DIM);
        ((float4*)xs)[k] = xrow[k];
    }
    float c = 0.0f;
    __syncthreads();

    for (int t = 0; t < T_SEQ; ++t) {
        // ---- z = b + x_t.Wcol + h.Ucol, then activation ----
        if (k < 4 * H1) {
            float acc0 = bias, acc1 = 0.0f, acc2 = 0.0f, acc3 = 0.0f;
#pragma unroll
            for (int q = 0; q < IN_DIM / 4; ++q) {
                float4 xv = ((const float4*)xs)[q];
                acc0 += xv.x * w1r[4 * q + 0];
                acc1 += xv.y * w1r[4 * q + 1];
                acc2 += xv.z * w1r[4 * q + 2];
                acc3 += xv.w * w1r[4 * q + 3];
            }
#pragma unroll
            for (int q = 0; q < H1 / 4; ++q) {
                float4 hv = ((const float4*)hs)[q];
                acc0 += hv.x * u1r[4 * q + 0];
                acc1 += hv.y * u1r[4 * q + 1];
                acc2 += hv.z * u1r[4 * q + 2];
                acc3 += hv.w * u1r[4 * q + 3];
            }
            float zv = (acc0 + acc1) + (acc2 + acc3);
            // Keras gate order i,f,g,o; g uses relu, others sigmoid.
            float a = (k >= 2 * H1 && k < 3 * H1) ? fmaxf(zv, 0.0f) : sigmoidf_(zv);
            zs[k] = a;
        }
        __syncthreads();

        // ---- gate funnel: c/h update by unit threads ----
        if (k < H1) {
            float i = zs[k];
            float f = zs[k + H1];
            float g = zs[k + 2 * H1];
            float o = zs[k + 3 * H1];
            c = f * c + i * g;
            float h = o * fmaxf(c, 0.0f);  // output activation relu
            hs[k] = h;
            h1out[((size_t)t * BATCH + b) * H1 + k] = h;
        }
        // stage x(t+1) (disjoint from z-compute reads: this side of the barrier)
        int tn = t + 1;
        if (tn < T_SEQ && k < IN_DIM / 4) {
            const float4* xrow = (const float4*)(x + ((size_t)b * T_SEQ + tn) * IN_DIM);
            ((float4*)xs)[k] = xrow[k];
        }
        __syncthreads();
    }
}

// ---------------- LSTM layer 2 ----------------
// grid: 512 blocks, block: 512 threads (8 waves), every thread owns a column.
__global__ __launch_bounds__(512, 1)
void lstm2_kernel(const float* __restrict__ h1in, // [T][B][100]
                  const float* __restrict__ W2,   // [100][512]
                  const float* __restrict__ U2,   // [128][512]
                  const float* __restrict__ b2,   // [512]
                  float* __restrict__ h2out)      // [B][128]
{
    const int b = blockIdx.x;
    const int k = threadIdx.x;  // 0..511

    __shared__ __align__(16) float ps[H1];      // staged h1 row (layer-1 output)
    __shared__ __align__(16) float hs[H2];
    __shared__ __align__(16) float zs[4 * H2];

    float w2r[H1];
    float u2r[H2];
    float bias = b2[k];
#pragma unroll
    for (int j = 0; j < H1; ++j) w2r[j] = W2[j * (4 * H2) + k];
#pragma unroll
    for (int j = 0; j < H2; ++j) u2r[j] = U2[j * (4 * H2) + k];

    if (k < H2) hs[k] = 0.0f;
    if (k < H1 / 4) {
        const float4* prow = (const float4*)(h1in + ((size_t)0 * BATCH + b) * H1);
        ((float4*)ps)[k] = prow[k];
    }
    float c = 0.0f;
    float hlast = 0.0f;
    __syncthreads();

    for (int t = 0; t < T_SEQ; ++t) {
        float acc0 = bias, acc1 = 0.0f, acc2 = 0.0f, acc3 = 0.0f;
#pragma unroll
        for (int q = 0; q < H1 / 4; ++q) {
            float4 pv = ((const float4*)ps)[q];
            acc0 += pv.x * w2r[4 * q + 0];
            acc1 += pv.y * w2r[4 * q + 1];
            acc2 += pv.z * w2r[4 * q + 2];
            acc3 += pv.w * w2r[4 * q + 3];
        }
#pragma unroll
        for (int q = 0; q < H2 / 4; ++q) {
            float4 hv = ((const float4*)hs)[q];
            acc0 += hv.x * u2r[4 * q + 0];
            acc1 += hv.y * u2r[4 * q + 1];
            acc2 += hv.z * u2r[4 * q + 2];
            acc3 += hv.w * u2r[4 * q + 3];
        }
        float zv = (acc0 + acc1) + (acc2 + acc3);
        float a = (k >= 2 * H2 && k < 3 * H2) ? fmaxf(zv, 0.0f) : sigmoidf_(zv);
        zs[k] = a;
        __syncthreads();

        if (k < H2) {
            float i = zs[k];
            float f = zs[k + H2];
            float g = zs[k + 2 * H2];
            float o = zs[k + 3 * H2];
            c = f * c + i * g;
            hlast = o * fmaxf(c, 0.0f);
            hs[k] = hlast;
        }
        int tn = t + 1;
        if (tn < T_SEQ && k < H1 / 4) {
            const float4* prow = (const float4*)(h1in + ((size_t)tn * BATCH + b) * H1);
            ((float4*)ps)[k] = prow[k];
        }
        __syncthreads();
    }

    if (k < H2) h2out[(size_t)b * H2 + k] = hlast;
}

// ---------------- Dense + softmax ----------------
// grid: 512 blocks, block: 64 threads (1 wave). threads k<19 compute logits.
__global__ __launch_bounds__(64, 1)
void dense_softmax_kernel(const float* __restrict__ h2, // [B][128]
                          const float* __restrict__ Wd, // [128][19]
                          const float* __restrict__ bd, // [19]
                          float* __restrict__ out)      // [B][19]
{
    const int b = blockIdx.x;
    const int k = threadIdx.x;

    __shared__ __align__(16) float hsm[H2];
    if (k < H2 / 4) {
        ((float4*)hsm)[k] = ((const float4*)(h2 + (size_t)b * H2))[k];
    }
    __syncthreads();

    float logit = -1e30f;
    if (k < NCLS) {
        float acc = bd[k];
#pragma unroll
        for (int d = 0; d < H2; ++d) acc += hsm[d] * Wd[d * NCLS + k];
        logit = acc;
    }
    // wave-64 butterfly max
    float m = logit;
#pragma unroll
    for (int off = 32; off >= 1; off >>= 1) m = fmaxf(m, __shfl_xor(m, off, 64));
    float e = (k < NCLS) ? __expf(logit - m) : 0.0f;
    float s = e;
#pragma unroll
    for (int off = 32; off >= 1; off >>= 1) s += __shfl_xor(s, off, 64);
    if (k < NCLS) out[(size_t)b * NCLS + k] = e / s;
}

extern "C" void kernel_launch(void* const* d_in, const int* in_sizes, int n_in,
                              void* d_out, int out_size, void* d_ws, size_t ws_size,
                              hipStream_t stream) {
    const float* x  = (const float*)d_in[0];
    const float* W1 = (const float*)d_in[1];
    const float* U1 = (const float*)d_in[2];
    const float* b1 = (const float*)d_in[3];
    const float* W2 = (const float*)d_in[4];
    const float* U2 = (const float*)d_in[5];
    const float* b2 = (const float*)d_in[6];
    const float* Wd = (const float*)d_in[7];
    const float* bd = (const float*)d_in[8];
    float* out = (float*)d_out;

    // workspace layout: h1_seq [T][B][100] f32, then h2 [B][128] f32 (~50.3 MB)
    float* h1buf = (float*)d_ws;
    float* h2buf = h1buf + (size_t)T_SEQ * BATCH * H1;

    hipLaunchKernelGGL(lstm1_kernel, dim3(BATCH), dim3(448), 0, stream,
                       x, W1, U1, b1, h1buf);
    hipLaunchKernelGGL(lstm2_kernel, dim3(BATCH), dim3(512), 0, stream,
                       h1buf, W2, U2, b2, h2buf);
    hipLaunchKernelGGL(dense_softmax_kernel, dim3(BATCH), dim3(64), 0, stream,
                       h2buf, Wd, bd, out);
}

// Round 2
// 1695.776 us; speedup vs baseline: 1.0047x; 1.0047x over previous
//
#include <hip/hip_runtime.h>
#include <math.h>

// TfLSTM: x[512,256,128] -> LSTM(100, relu) -> LSTM(128, relu, last) -> Dense(19) -> softmax
// Round 2: split feedforward projections (x@W+b) into parallel fp32 GEMMs;
// recurrence kernels do only h@U with weights truly register-resident
// (C=2 cols/thread rec1; 4-way k-split rec2 so regs<=200/128, no spill).
// Fallback to round-1 fused kernels if ws_size < 321.2 MB.

#define T_SEQ 256
#define BATCH 512
#define IN_DIM 128
#define H1 100
#define H2 128
#define NCLS 19

__device__ __forceinline__ float sigmoidf_(float x) {
    return 1.0f / (1.0f + __expf(-x));
}

// =================== projection GEMM ===================
// out[orow][n] = bias[n] + sum_k A[r][k] * W[k][n]
// r = blockIdx.x*128 + local row; orow = SWAP ? (r&255)*512 + (r>>8) : r.
// Tile 128x128, micro 8x8, k-chunks of 32, LDS-transposed A.
template<int K, int N, bool SWAP>
__global__ __launch_bounds__(256, 2)
void proj_kernel(const float* __restrict__ A, const float* __restrict__ W,
                 const float* __restrict__ bias, float* __restrict__ out)
{
    constexpr int LD = 132;  // padded LDS stride (x4B: avoids pow2 conflicts, keeps 16B align)
    __shared__ __align__(16) float As[32 * LD];  // [k][row]
    __shared__ __align__(16) float Ws[32 * LD];  // [k][col]
    const int tid = threadIdx.x;
    const int r0 = blockIdx.x * 128;
    const int c0 = blockIdx.y * 128;
    const int ty = tid >> 4, tx = tid & 15;

    float acc[8][8];
#pragma unroll
    for (int i = 0; i < 8; ++i)
#pragma unroll
        for (int j = 0; j < 8; ++j) acc[i][j] = 0.0f;

    for (int kk = 0; kk < K; kk += 32) {
        __syncthreads();
        // stage A chunk, transposed: As[k][row]
#pragma unroll
        for (int i = 0; i < 4; ++i) {
            int idx = tid + i * 256;          // 1024 float4 slots: 128 rows x 8 kgroups
            int row = idx >> 3, kg = idx & 7;
            int k = kk + kg * 4;
            float4 v = make_float4(0.f, 0.f, 0.f, 0.f);
            if (k < K) v = *(const float4*)&A[(size_t)(r0 + row) * K + k];
            As[(kg * 4 + 0) * LD + row] = v.x;
            As[(kg * 4 + 1) * LD + row] = v.y;
            As[(kg * 4 + 2) * LD + row] = v.z;
            As[(kg * 4 + 3) * LD + row] = v.w;
        }
        // stage W chunk: Ws[k][col]
#pragma unroll
        for (int i = 0; i < 4; ++i) {
            int idx = tid + i * 256;          // 1024 float4 slots: 32 k x 32 colgroups
            int k = idx >> 5, cg = idx & 31;
            int gk = kk + k, gc = c0 + cg * 4;
            float4 v = make_float4(0.f, 0.f, 0.f, 0.f);
            if (gk < K && gc < N) v = *(const float4*)&W[(size_t)gk * N + gc];
            *(float4*)&Ws[k * LD + cg * 4] = v;
        }
        __syncthreads();
#pragma unroll
        for (int k = 0; k < 32; ++k) {
            float4 a0 = *(const float4*)&As[k * LD + ty * 8];
            float4 a1 = *(const float4*)&As[k * LD + ty * 8 + 4];
            float4 b0 = *(const float4*)&Ws[k * LD + tx * 8];
            float4 b1 = *(const float4*)&Ws[k * LD + tx * 8 + 4];
            float av[8] = {a0.x, a0.y, a0.z, a0.w, a1.x, a1.y, a1.z, a1.w};
            float bv[8] = {b0.x, b0.y, b0.z, b0.w, b1.x, b1.y, b1.z, b1.w};
#pragma unroll
            for (int i = 0; i < 8; ++i)
#pragma unroll
                for (int j = 0; j < 8; ++j) acc[i][j] += av[i] * bv[j];
        }
    }

    // epilogue: + bias, store with col mask
    float bv[8];
#pragma unroll
    for (int j = 0; j < 8; ++j) {
        int c = c0 + tx * 8 + j;
        bv[j] = (c < N) ? bias[c] : 0.0f;
    }
#pragma unroll
    for (int i = 0; i < 8; ++i) {
        int r = r0 + ty * 8 + i;
        size_t orow = SWAP ? ((size_t)(r & 255) * BATCH + (r >> 8)) : (size_t)r;
        int cb = c0 + tx * 8;
        if (cb < N) {
            float4 v = make_float4(acc[i][0] + bv[0], acc[i][1] + bv[1],
                                   acc[i][2] + bv[2], acc[i][3] + bv[3]);
            *(float4*)&out[orow * N + cb] = v;
        }
        if (cb + 4 < N) {
            float4 v = make_float4(acc[i][4] + bv[4], acc[i][5] + bv[5],
                                   acc[i][6] + bv[6], acc[i][7] + bv[7]);
            *(float4*)&out[orow * N + cb + 4] = v;
        }
    }
}

// =================== recurrence, layer 1 ===================
// z = zx[t] (+bias already in zx) + h @ U1. Thread k<200 owns cols {k, k+200}
// (i,g for k<100; f,o for k>=100). 200 U-regs. 2 barriers/step.
__global__ __launch_bounds__(256, 2)
void rec1_kernel(const float* __restrict__ zx,   // [T][B][400] (bias included)
                 const float* __restrict__ U1,   // [100][400]
                 float* __restrict__ h1seq)      // [T][B][100]
{
    const int row = blockIdx.x;
    const int k = threadIdx.x;
    __shared__ __align__(16) float hs[H1];
    __shared__ __align__(8) float fo[2 * H1];

    float u0[H1], u1[H1];
    const int c0 = k, c1 = k + 200;
    if (k < 200) {
#pragma unroll
        for (int j = 0; j < H1; ++j) {
            u0[j] = U1[j * 400 + c0];
            u1[j] = U1[j * 400 + c1];
        }
    }
    if (k < H1) hs[k] = 0.0f;
    float cst = 0.0f;
    float zc0 = 0.f, zc1 = 0.f;
    if (k < 200) {
        zc0 = zx[(size_t)row * 400 + c0];
        zc1 = zx[(size_t)row * 400 + c1];
    }
    __syncthreads();

    for (int t = 0; t < T_SEQ; ++t) {
        // prefetch next step's zx
        int tn = (t + 1 < T_SEQ) ? t + 1 : t;
        float zn0 = 0.f, zn1 = 0.f;
        if (k < 200) {
            const float* p = &zx[((size_t)tn * BATCH + row) * 400];
            zn0 = p[c0];
            zn1 = p[c1];
        }
        float a0 = zc0, a1 = zc1;
        if (k < 200) {
#pragma unroll
            for (int q = 0; q < H1 / 4; ++q) {
                float4 h4 = *(const float4*)&hs[4 * q];
                a0 += h4.x * u0[4 * q] + h4.y * u0[4 * q + 1] + h4.z * u0[4 * q + 2] + h4.w * u0[4 * q + 3];
                a1 += h4.x * u1[4 * q] + h4.y * u1[4 * q + 1] + h4.z * u1[4 * q + 2] + h4.w * u1[4 * q + 3];
            }
            a0 = sigmoidf_(a0);                                   // i or f
            a1 = (k < H1) ? fmaxf(a1, 0.0f) : sigmoidf_(a1);      // g (relu) or o
            if (k >= H1) *(float2*)&fo[2 * (k - H1)] = make_float2(a0, a1);
        }
        __syncthreads();
        if (k < H1) {
            float2 f_o = *(const float2*)&fo[2 * k];
            cst = f_o.x * cst + a0 * a1;          // c = f*c + i*g
            float h = f_o.y * fmaxf(cst, 0.0f);   // h = o*relu(c)
            hs[k] = h;
            h1seq[((size_t)t * BATCH + row) * H1 + k] = h;
        }
        __syncthreads();
        zc0 = zn0;
        zc1 = zn1;
    }
}

// =================== recurrence, layer 2 ===================
// 4-way k-split: thread (kq=tid>>7, cl=tid&127) accumulates partial dots over
// k in [kq*32, kq*32+32) for cols {cl, cl+128, cl+256, cl+384}. 128 U-regs.
// Reduce through LDS zp, activate, funnel. 3 barriers/step.
__global__ __launch_bounds__(512, 2)
void rec2_kernel(const float* __restrict__ zx,   // [T][B][512] (bias included)
                 const float* __restrict__ U2,   // [128][512]
                 float* __restrict__ h2out)      // [B][128]
{
    const int row = blockIdx.x;
    const int tid = threadIdx.x;   // 0..511
    const int kq = tid >> 7;
    const int cl = tid & 127;
    __shared__ __align__(16) float hs[H2];
    __shared__ float zp[4 * 512];
    __shared__ float za[512];

    float u[4][32];
#pragma unroll
    for (int m = 0; m < 4; ++m)
#pragma unroll
        for (int q = 0; q < 32; ++q)
            u[m][q] = U2[(size_t)(kq * 32 + q) * 512 + cl + 128 * m];

    if (tid < H2) hs[tid] = 0.0f;
    float cst = 0.0f;
    float zc = zx[(size_t)row * 512 + tid];
    __syncthreads();

    for (int t = 0; t < T_SEQ; ++t) {
        int tn = (t + 1 < T_SEQ) ? t + 1 : t;
        float zn = zx[((size_t)tn * BATCH + row) * 512 + tid];

        float acc0 = 0.f, acc1 = 0.f, acc2 = 0.f, acc3 = 0.f;
#pragma unroll
        for (int j = 0; j < 8; ++j) {
            float4 h4 = *(const float4*)&hs[kq * 32 + 4 * j];
            acc0 += h4.x * u[0][4 * j] + h4.y * u[0][4 * j + 1] + h4.z * u[0][4 * j + 2] + h4.w * u[0][4 * j + 3];
            acc1 += h4.x * u[1][4 * j] + h4.y * u[1][4 * j + 1] + h4.z * u[1][4 * j + 2] + h4.w * u[1][4 * j + 3];
            acc2 += h4.x * u[2][4 * j] + h4.y * u[2][4 * j + 1] + h4.z * u[2][4 * j + 2] + h4.w * u[2][4 * j + 3];
            acc3 += h4.x * u[3][4 * j] + h4.y * u[3][4 * j + 1] + h4.z * u[3][4 * j + 2] + h4.w * u[3][4 * j + 3];
        }
        zp[kq * 512 + cl]       = acc0;
        zp[kq * 512 + cl + 128] = acc1;
        zp[kq * 512 + cl + 256] = acc2;
        zp[kq * 512 + cl + 384] = acc3;
        __syncthreads();

        float z = zc + zp[tid] + zp[512 + tid] + zp[1024 + tid] + zp[1536 + tid];
        float a = (tid >= 2 * H2 && tid < 3 * H2) ? fmaxf(z, 0.0f) : sigmoidf_(z);
        za[tid] = a;
        __syncthreads();

        if (tid < H2) {
            float i = za[tid], f = za[tid + 128], g = za[tid + 256], o = za[tid + 384];
            cst = f * cst + i * g;
            float h = o * fmaxf(cst, 0.0f);
            hs[tid] = h;
            if (t == T_SEQ - 1) h2out[(size_t)row * H2 + tid] = h;
        }
        __syncthreads();
        zc = zn;
    }
}

// =================== dense + softmax ===================
__global__ __launch_bounds__(64, 1)
void dense_softmax_kernel(const float* __restrict__ h2, const float* __restrict__ Wd,
                          const float* __restrict__ bd, float* __restrict__ out)
{
    const int b = blockIdx.x;
    const int k = threadIdx.x;
    __shared__ __align__(16) float hsm[H2];
    if (k < H2 / 4) ((float4*)hsm)[k] = ((const float4*)(h2 + (size_t)b * H2))[k];
    __syncthreads();

    float logit = -1e30f;
    if (k < NCLS) {
        float acc = bd[k];
#pragma unroll
        for (int d = 0; d < H2; ++d) acc += hsm[d] * Wd[d * NCLS + k];
        logit = acc;
    }
    float m = logit;
#pragma unroll
    for (int off = 32; off >= 1; off >>= 1) m = fmaxf(m, __shfl_xor(m, off, 64));
    float e = (k < NCLS) ? __expf(logit - m) : 0.0f;
    float s = e;
#pragma unroll
    for (int off = 32; off >= 1; off >>= 1) s += __shfl_xor(s, off, 64);
    if (k < NCLS) out[(size_t)b * NCLS + k] = e / s;
}

// =================== round-1 fallback kernels ===================
__global__ __launch_bounds__(448, 1)
void lstm1_fb(const float* __restrict__ x, const float* __restrict__ W1,
              const float* __restrict__ U1, const float* __restrict__ b1,
              float* __restrict__ h1out)
{
    const int b = blockIdx.x;
    const int k = threadIdx.x;
    __shared__ __align__(16) float xs[IN_DIM];
    __shared__ __align__(16) float hs[H1];
    __shared__ __align__(16) float zs[4 * H1];
    float w1r[IN_DIM];
    float u1r[H1];
    float bias = 0.0f;
    if (k < 4 * H1) {
        bias = b1[k];
#pragma unroll
        for (int d = 0; d < IN_DIM; ++d) w1r[d] = W1[d * (4 * H1) + k];
#pragma unroll
        for (int j = 0; j < H1; ++j) u1r[j] = U1[j * (4 * H1) + k];
    }
    if (k < H1) hs[k] = 0.0f;
    if (k < IN_DIM / 4)
        ((float4*)xs)[k] = ((const float4*)(x + ((size_t)b * T_SEQ) * IN_DIM))[k];
    float c = 0.0f;
    __syncthreads();
    for (int t = 0; t < T_SEQ; ++t) {
        if (k < 4 * H1) {
            float acc0 = bias, acc1 = 0.f, acc2 = 0.f, acc3 = 0.f;
#pragma unroll
            for (int q = 0; q < IN_DIM / 4; ++q) {
                float4 xv = ((const float4*)xs)[q];
                acc0 += xv.x * w1r[4 * q]; acc1 += xv.y * w1r[4 * q + 1];
                acc2 += xv.z * w1r[4 * q + 2]; acc3 += xv.w * w1r[4 * q + 3];
            }
#pragma unroll
            for (int q = 0; q < H1 / 4; ++q) {
                float4 hv = ((const float4*)hs)[q];
                acc0 += hv.x * u1r[4 * q]; acc1 += hv.y * u1r[4 * q + 1];
                acc2 += hv.z * u1r[4 * q + 2]; acc3 += hv.w * u1r[4 * q + 3];
            }
            float zv = (acc0 + acc1) + (acc2 + acc3);
            zs[k] = (k >= 2 * H1 && k < 3 * H1) ? fmaxf(zv, 0.0f) : sigmoidf_(zv);
        }
        __syncthreads();
        if (k < H1) {
            float i = zs[k], f = zs[k + H1], g = zs[k + 2 * H1], o = zs[k + 3 * H1];
            c = f * c + i * g;
            float h = o * fmaxf(c, 0.0f);
            hs[k] = h;
            h1out[((size_t)t * BATCH + b) * H1 + k] = h;
        }
        int tn = t + 1;
        if (tn < T_SEQ && k < IN_DIM / 4)
            ((float4*)xs)[k] = ((const float4*)(x + ((size_t)b * T_SEQ + tn) * IN_DIM))[k];
        __syncthreads();
    }
}

__global__ __launch_bounds__(512, 1)
void lstm2_fb(const float* __restrict__ h1in, const float* __restrict__ W2,
              const float* __restrict__ U2, const float* __restrict__ b2,
              float* __restrict__ h2out)
{
    const int b = blockIdx.x;
    const int k = threadIdx.x;
    __shared__ __align__(16) float ps[H1];
    __shared__ __align__(16) float hs[H2];
    __shared__ __align__(16) float zs[4 * H2];
    float w2r[H1];
    float u2r[H2];
    float bias = b2[k];
#pragma unroll
    for (int j = 0; j < H1; ++j) w2r[j] = W2[j * (4 * H2) + k];
#pragma unroll
    for (int j = 0; j < H2; ++j) u2r[j] = U2[j * (4 * H2) + k];
    if (k < H2) hs[k] = 0.0f;
    if (k < H1 / 4)
        ((float4*)ps)[k] = ((const float4*)(h1in + (size_t)b * H1))[k];
    float c = 0.0f;
    float hlast = 0.0f;
    __syncthreads();
    for (int t = 0; t < T_SEQ; ++t) {
        float acc0 = bias, acc1 = 0.f, acc2 = 0.f, acc3 = 0.f;
#pragma unroll
        for (int q = 0; q < H1 / 4; ++q) {
            float4 pv = ((const float4*)ps)[q];
            acc0 += pv.x * w2r[4 * q]; acc1 += pv.y * w2r[4 * q + 1];
            acc2 += pv.z * w2r[4 * q + 2]; acc3 += pv.w * w2r[4 * q + 3];
        }
#pragma unroll
        for (int q = 0; q < H2 / 4; ++q) {
            float4 hv = ((const float4*)hs)[q];
            acc0 += hv.x * u2r[4 * q]; acc1 += hv.y * u2r[4 * q + 1];
            acc2 += hv.z * u2r[4 * q + 2]; acc3 += hv.w * u2r[4 * q + 3];
        }
        float zv = (acc0 + acc1) + (acc2 + acc3);
        zs[k] = (k >= 2 * H2 && k < 3 * H2) ? fmaxf(zv, 0.0f) : sigmoidf_(zv);
        __syncthreads();
        if (k < H2) {
            float i = zs[k], f = zs[k + H2], g = zs[k + 2 * H2], o = zs[k + 3 * H2];
            c = f * c + i * g;
            hlast = o * fmaxf(c, 0.0f);
            hs[k] = hlast;
        }
        int tn = t + 1;
        if (tn < T_SEQ && k < H1 / 4)
            ((float4*)ps)[k] = ((const float4*)(h1in + ((size_t)tn * BATCH + b) * H1))[k];
        __syncthreads();
    }
    if (k < H2) h2out[(size_t)b * H2 + k] = hlast;
}

extern "C" void kernel_launch(void* const* d_in, const int* in_sizes, int n_in,
                              void* d_out, int out_size, void* d_ws, size_t ws_size,
                              hipStream_t stream) {
    const float* x  = (const float*)d_in[0];
    const float* W1 = (const float*)d_in[1];
    const float* U1 = (const float*)d_in[2];
    const float* b1 = (const float*)d_in[3];
    const float* W2 = (const float*)d_in[4];
    const float* U2 = (const float*)d_in[5];
    const float* b2 = (const float*)d_in[6];
    const float* Wd = (const float*)d_in[7];
    const float* bd = (const float*)d_in[8];
    float* out = (float*)d_out;

    const size_t zx_elems = (size_t)T_SEQ * BATCH * 512;   // shared zx1/zx2 buffer
    const size_t h1_elems = (size_t)T_SEQ * BATCH * H1;
    const size_t h2_elems = (size_t)BATCH * H2;
    const size_t need = (zx_elems + h1_elems + h2_elems) * sizeof(float);  // ~321.2 MB

    if (ws_size >= need) {
        float* zxbuf = (float*)d_ws;
        float* h1buf = zxbuf + zx_elems;
        float* h2buf = h1buf + h1_elems;

        // zx1 = x @ W1 + b1  -> [T][B][400]
        hipLaunchKernelGGL((proj_kernel<IN_DIM, 4 * H1, true>), dim3(1024, 4), dim3(256), 0, stream,
                           x, W1, b1, zxbuf);
        hipLaunchKernelGGL(rec1_kernel, dim3(BATCH), dim3(256), 0, stream,
                           zxbuf, U1, h1buf);
        // zx2 = h1seq @ W2 + b2 -> [T][B][512] (overwrites zx1, safe after rec1)
        hipLaunchKernelGGL((proj_kernel<H1, 4 * H2, false>), dim3(1024, 4), dim3(256), 0, stream,
                           h1buf, W2, b2, zxbuf);
        hipLaunchKernelGGL(rec2_kernel, dim3(BATCH), dim3(512), 0, stream,
                           zxbuf, U2, h2buf);
        hipLaunchKernelGGL(dense_softmax_kernel, dim3(BATCH), dim3(64), 0, stream,
                           h2buf, Wd, bd, out);
    } else {
        // fallback: round-1 fused kernels (needs ~52.7 MB)
        float* h1buf = (float*)d_ws;
        float* h2buf = h1buf + h1_elems;
        hipLaunchKernelGGL(lstm1_fb, dim3(BATCH), dim3(448), 0, stream, x, W1, U1, b1, h1buf);
        hipLaunchKernelGGL(lstm2_fb, dim3(BATCH), dim3(512), 0, stream, h1buf, W2, U2, b2, h2buf);
        hipLaunchKernelGGL(dense_softmax_kernel, dim3(BATCH), dim3(64), 0, stream, h2buf, Wd, bd, out);
    }
}